// Round 1
// baseline (354.631 us; speedup 1.0000x reference)
//
#include <hip/hip_runtime.h>
#include <stdint.h>

typedef __attribute__((ext_vector_type(4))) float          f32x4;
typedef __attribute__((ext_vector_type(8))) short          bf16x8;
typedef __attribute__((ext_vector_type(8))) unsigned short u16x8;
typedef __attribute__((ext_vector_type(4))) unsigned short u16x4;

static __device__ __forceinline__ unsigned short f2bf(float f){
  uint32_t u = __builtin_bit_cast(uint32_t, f);
  u += 0x7FFFu + ((u >> 16) & 1u);          // RNE
  return (unsigned short)(u >> 16);
}
static __device__ __forceinline__ float bf2f(unsigned short h){
  uint32_t u = ((uint32_t)h) << 16;
  return __builtin_bit_cast(float, u);
}

// ---------------- elementwise convert f32 -> bf16 (8/thread) ----------------
__global__ void k_cvt(const float* __restrict__ in, unsigned short* __restrict__ out, long n){
  long i = ((long)blockIdx.x * blockDim.x + threadIdx.x) * 8;
  if (i >= n) return;
  const f32x4* p = (const f32x4*)(in + i);
  f32x4 a = p[0], b = p[1];
  u16x8 o;
  #pragma unroll
  for (int j = 0; j < 4; j++){ o[j] = f2bf(a[j]); o[4+j] = f2bf(b[j]); }
  *(u16x8*)(out + i) = o;
}

// ---------------- tiled transpose+convert: in[R][C] f32 -> out[C][R] bf16 ----
__global__ void k_tconv(const float* __restrict__ in, unsigned short* __restrict__ out, int R, int C){
  __shared__ float tl[64][65];
  const int c0 = blockIdx.x * 64, r0 = blockIdx.y * 64;
  const int t = threadIdx.x;
  {
    const int lr = t >> 2, lc = (t & 3) * 16;
    const f32x4* s = (const f32x4*)(in + (long)(r0 + lr) * C + c0 + lc);
    #pragma unroll
    for (int q = 0; q < 4; q++){
      f32x4 v = s[q];
      #pragma unroll
      for (int j = 0; j < 4; j++) tl[lr][lc + q*4 + j] = v[j];
    }
  }
  __syncthreads();
  {
    const int oc = t >> 2, orr = (t & 3) * 16;
    u16x8 o0, o1;
    #pragma unroll
    for (int i = 0; i < 8; i++){ o0[i] = f2bf(tl[orr + i][oc]); o1[i] = f2bf(tl[orr + 8 + i][oc]); }
    u16x8* dst = (u16x8*)(out + (long)(c0 + oc) * R + r0 + orr);
    dst[0] = o0; dst[1] = o1;
  }
}

// ---------------- m97-style 128x128 bf16 GEMM, BK=32 ------------------------
// MODE 0: A=x_bf[32768][768], BT=WT[2304][768] -> QT/KT (transposed) + V (natural)
// MODE 1: A=out1[32768][768], BT=WpT[768][768] -> OUTF fp32 + bias
template<int MODE>
__global__ __launch_bounds__(256)
void k_gemm(const unsigned short* __restrict__ A, const unsigned short* __restrict__ BT,
            unsigned short* __restrict__ QT, unsigned short* __restrict__ KT,
            unsigned short* __restrict__ V, float* __restrict__ OUTF,
            const float* __restrict__ bias)
{
  __shared__ unsigned short As[128 * 32];
  __shared__ unsigned short Bs[128 * 32];
  const int m0 = blockIdx.y * 128;
  const int j0 = blockIdx.x * 128;
  const int t = threadIdx.x;
  const int lane = t & 63;
  const int w = t >> 6, wm = w >> 1, wn = w & 1;

  f32x4 acc[4][4] = {};

  for (int kt = 0; kt < 768; kt += 32){
    if (kt) __syncthreads();
    #pragma unroll
    for (int i = 0; i < 2; i++){
      const char* ga = (const char*)A  + (long)(m0 + i*64 + (t >> 2)) * 1536 + kt*2 + (t & 3) * 16;
      const char* gb = (const char*)BT + (long)(j0 + i*64 + (t >> 2)) * 1536 + kt*2 + (t & 3) * 16;
      char* la = (char*)As + i*4096 + (t & 0xC0) * 16;   // wave-uniform base
      char* lb = (char*)Bs + i*4096 + (t & 0xC0) * 16;
      __builtin_amdgcn_global_load_lds((const __attribute__((address_space(1))) unsigned int*)ga,
                                       (__attribute__((address_space(3))) unsigned int*)la, 16, 0, 0);
      __builtin_amdgcn_global_load_lds((const __attribute__((address_space(1))) unsigned int*)gb,
                                       (__attribute__((address_space(3))) unsigned int*)lb, 16, 0, 0);
    }
    __syncthreads();
    bf16x8 af[4], bfr[4];
    #pragma unroll
    for (int mi = 0; mi < 4; mi++)
      af[mi]  = *(const bf16x8*)&As[(wm*64 + mi*16 + (lane & 15)) * 32 + (lane >> 4) * 8];
    #pragma unroll
    for (int ni = 0; ni < 4; ni++)
      bfr[ni] = *(const bf16x8*)&Bs[(wn*64 + ni*16 + (lane & 15)) * 32 + (lane >> 4) * 8];
    #pragma unroll
    for (int mi = 0; mi < 4; mi++)
      #pragma unroll
      for (int ni = 0; ni < 4; ni++)
        acc[mi][ni] = __builtin_amdgcn_mfma_f32_16x16x32_bf16(af[mi], bfr[ni], acc[mi][ni], 0, 0, 0);
  }

  if (MODE == 0){
    const int b  = m0 >> 12;
    if (j0 < 1536){
      // q/k region: write transposed into QT/KT[b][h][c][n]; 4 regs = 4 consecutive n
      const int nb = (m0 & 4095) + wm*64 + (lane >> 4) * 4;
      #pragma unroll
      for (int mi = 0; mi < 4; mi++){
        #pragma unroll
        for (int ni = 0; ni < 4; ni++){
          const int jc = j0 + wn*64 + ni*16 + (lane & 15);
          const int s  = (jc >= 768);
          const int jl = jc - s * 768;
          const int h  = jl / 48;
          const int c  = jl - h * 48;
          unsigned short* dst = (s ? KT : QT) + (((long)(b*16 + h) * 48 + c) << 12) + (nb + mi*16);
          u16x4 pk;
          #pragma unroll
          for (int r = 0; r < 4; r++) pk[r] = f2bf(acc[mi][ni][r]);
          *(u16x4*)dst = pk;
        }
      }
    } else {
      #pragma unroll
      for (int mi = 0; mi < 4; mi++){
        #pragma unroll
        for (int ni = 0; ni < 4; ni++){
          const int jv = (j0 - 1536) + wn*64 + ni*16 + (lane & 15);
          const long mr = (long)m0 + wm*64 + mi*16 + (lane >> 4) * 4;
          #pragma unroll
          for (int r = 0; r < 4; r++) V[(mr + r) * 768 + jv] = f2bf(acc[mi][ni][r]);
        }
      }
    }
  } else {
    #pragma unroll
    for (int mi = 0; mi < 4; mi++){
      #pragma unroll
      for (int ni = 0; ni < 4; ni++){
        const int jc = j0 + wn*64 + ni*16 + (lane & 15);
        const float bv = bias[jc];
        const long mr = (long)m0 + wm*64 + mi*16 + (lane >> 4) * 4;
        #pragma unroll
        for (int r = 0; r < 4; r++) OUTF[(mr + r) * 768 + jc] = acc[mi][ni][r] + bv;
      }
    }
  }
}

// ---------------- per-row inverse L2 norm over QT||KT rows (4096 each) ------
__global__ void k_norm(const unsigned short* __restrict__ QTKT, float* __restrict__ invn){
  const long row = blockIdx.x;
  const unsigned short* p = QTKT + (row << 12);
  const int l = threadIdx.x;   // 64 threads = 1 wave
  float ss = 0.f;
  #pragma unroll
  for (int i = 0; i < 8; i++){
    u16x8 v = *(const u16x8*)(p + (i*64 + l) * 8);
    #pragma unroll
    for (int j = 0; j < 8; j++){ float f = bf2f(v[j]); ss += f * f; }
  }
  #pragma unroll
  for (int off = 32; off > 0; off >>= 1) ss += __shfl_down(ss, off);
  if (l == 0) invn[row] = 1.0f / fmaxf(sqrtf(ss), 1e-12f);
}

// ---------------- S partials: per (bh, ksp) 48x48 over 1024 n ---------------
__global__ __launch_bounds__(256)
void k_attn_part(const unsigned short* __restrict__ QT, const unsigned short* __restrict__ KT,
                 float* __restrict__ Spart)
{
  __shared__ float Sl[4][2304];
  const int bh = blockIdx.x, ksp = blockIdx.y;
  const int t = threadIdx.x, lane = t & 63, w = t >> 6;
  const unsigned short* qb = QT + ((long)bh * 48 << 12);
  const unsigned short* kb = KT + ((long)bh * 48 << 12);
  const int n00 = ksp * 1024 + w * 256;
  f32x4 acc[3][3] = {};
  for (int kt = 0; kt < 256; kt += 32){
    bf16x8 af[3], bfr[3];
    #pragma unroll
    for (int ci = 0; ci < 3; ci++)
      af[ci]  = *(const bf16x8*)(qb + ((long)(ci*16 + (lane & 15)) << 12) + n00 + kt + (lane >> 4) * 8);
    #pragma unroll
    for (int di = 0; di < 3; di++)
      bfr[di] = *(const bf16x8*)(kb + ((long)(di*16 + (lane & 15)) << 12) + n00 + kt + (lane >> 4) * 8);
    #pragma unroll
    for (int ci = 0; ci < 3; ci++)
      #pragma unroll
      for (int di = 0; di < 3; di++)
        acc[ci][di] = __builtin_amdgcn_mfma_f32_16x16x32_bf16(af[ci], bfr[di], acc[ci][di], 0, 0, 0);
  }
  #pragma unroll
  for (int ci = 0; ci < 3; ci++)
    #pragma unroll
    for (int di = 0; di < 3; di++)
      #pragma unroll
      for (int r = 0; r < 4; r++)
        Sl[w][(ci*16 + (lane >> 4)*4 + r) * 48 + di*16 + (lane & 15)] = acc[ci][di][r];
  __syncthreads();
  float* outp = Spart + ((long)ksp * 128 + bh) * 2304;
  for (int idx = t; idx < 2304; idx += 256)
    outp[idx] = Sl[0][idx] + Sl[1][idx] + Sl[2][idx] + Sl[3][idx];
}

// ---------------- reduce partials, scale by invnorms*temp, softmax ----------
__global__ void k_softmax(const float* __restrict__ Spart, const float* __restrict__ invn,
                          const float* __restrict__ temp, unsigned short* __restrict__ attn)
{
  const int bh = blockIdx.x, b = bh >> 4, h = bh & 15;
  const int c = threadIdx.x;   // 64 threads, 48 active
  (void)b;
  if (c < 48){
    const float invq = invn[bh*48 + c];
    const float tq = temp[h];
    float row[48];
    #pragma unroll
    for (int d = 0; d < 48; d++){
      long base = ((long)bh * 48 + c) * 48 + d;
      float v = Spart[base] + Spart[base + 128L*2304] + Spart[base + 256L*2304] + Spart[base + 384L*2304];
      row[d] = v * invq * invn[6144 + bh*48 + d] * tq;
    }
    float mx = -1e30f;
    #pragma unroll
    for (int d = 0; d < 48; d++) mx = fmaxf(mx, row[d]);
    float s = 0.f;
    #pragma unroll
    for (int d = 0; d < 48; d++){ row[d] = expf(row[d] - mx); s += row[d]; }
    const float inv = 1.0f / s;
    unsigned short* o = attn + ((long)bh * 48 + c) * 64;
    #pragma unroll
    for (int d = 0; d < 48; d++) o[d] = f2bf(row[d] * inv);
    #pragma unroll
    for (int d = 48; d < 64; d++) o[d] = 0;
  }
}

// ---------------- AV: out1[m][h*48+c] = sum_d v[m][d]*attn[c][d] ------------
__global__ __launch_bounds__(256)
void k_av(const unsigned short* __restrict__ V, const unsigned short* __restrict__ attn,
          unsigned short* __restrict__ out1)
{
  const int gid = blockIdx.x;
  const int nt = gid & 15, bh = gid >> 4, b = bh >> 4, h = bh & 15;
  const int t = threadIdx.x, lane = t & 63, w = t >> 6;
  const int n0 = nt * 256 + w * 64;
  const unsigned short* vb = V + (long)b * 4096 * 768 + h * 48;
  const unsigned short* ab = attn + (long)bh * 48 * 64;
  f32x4 acc[4][3] = {};
  #pragma unroll
  for (int kt = 0; kt < 64; kt += 32){
    bf16x8 bfr[3];
    #pragma unroll
    for (int ci = 0; ci < 3; ci++)
      bfr[ci] = *(const bf16x8*)(ab + (ci*16 + (lane & 15)) * 64 + kt + (lane >> 4) * 8);
    #pragma unroll
    for (int nf = 0; nf < 4; nf++){
      bf16x8 a = *(const bf16x8*)(vb + (long)(n0 + nf*16 + (lane & 15)) * 768 + kt + (lane >> 4) * 8);
      #pragma unroll
      for (int ci = 0; ci < 3; ci++)
        acc[nf][ci] = __builtin_amdgcn_mfma_f32_16x16x32_bf16(a, bfr[ci], acc[nf][ci], 0, 0, 0);
    }
  }
  #pragma unroll
  for (int nf = 0; nf < 4; nf++)
    #pragma unroll
    for (int ci = 0; ci < 3; ci++)
      #pragma unroll
      for (int r = 0; r < 4; r++){
        long m = (long)b * 4096 + n0 + nf*16 + (lane >> 4)*4 + r;
        out1[m * 768 + h*48 + ci*16 + (lane & 15)] = f2bf(acc[nf][ci][r]);
      }
}

extern "C" void kernel_launch(void* const* d_in, const int* in_sizes, int n_in,
                              void* d_out, int out_size, void* d_ws, size_t ws_size,
                              hipStream_t stream)
{
  (void)in_sizes; (void)n_in; (void)out_size; (void)ws_size;
  const float* x      = (const float*)d_in[0];
  const float* w_qkv  = (const float*)d_in[1];
  const float* temp   = (const float*)d_in[2];
  const float* w_proj = (const float*)d_in[3];
  const float* b_proj = (const float*)d_in[4];
  float* outF = (float*)d_out;

  char* ws = (char*)d_ws;
  size_t off = 0;
  auto alloc = [&](size_t bytes)->char*{ char* p = ws + off; off += (bytes + 255) & ~(size_t)255; return p; };

  unsigned short* x_bf = (unsigned short*)alloc(50331648);            // [32768][768] bf16
  unsigned short* WT   = (unsigned short*)alloc(3538944);             // [2304][768] bf16
  unsigned short* WpT  = (unsigned short*)alloc(1179648);             // [768][768] bf16
  unsigned short* QT   = (unsigned short*)alloc(100663296);           // QT||KT [6144][4096] bf16 each
  unsigned short* KT   = QT + (long)6144 * 4096;
  unsigned short* V    = (unsigned short*)alloc(50331648 + 2048);     // [32768][768] bf16 + slack row
  float* invn          = (float*)alloc(12288 * 4);                    // [2][8][16][48]
  float* Spart         = (float*)alloc(4L * 128 * 2304 * 4);          // [4][128][48][48] f32
  unsigned short* attnb= (unsigned short*)alloc(128L * 48 * 64 * 2);  // [128][48][64] bf16, zero-padded
  unsigned short* out1 = QT;   // alias: QT fully consumed before AV writes

  // zero the V slack row (read by AV's K=64 padding path; x0 attn so value irrelevant but must be finite)
  hipMemsetAsync(V + 25165824, 0, 2048, stream);

  k_cvt<<<12288, 256, 0, stream>>>(x, x_bf, 25165824L);
  k_tconv<<<dim3(36, 12), 256, 0, stream>>>(w_qkv, WT, 768, 2304);
  k_tconv<<<dim3(12, 12), 256, 0, stream>>>(w_proj, WpT, 768, 768);
  k_gemm<0><<<dim3(18, 256), 256, 0, stream>>>(x_bf, WT, QT, KT, V, nullptr, nullptr);
  k_norm<<<12288, 64, 0, stream>>>(QT, invn);
  k_attn_part<<<dim3(128, 4), 256, 0, stream>>>(QT, KT, Spart);
  k_softmax<<<128, 64, 0, stream>>>(Spart, invn, temp, attnb);
  k_av<<<2048, 256, 0, stream>>>(V, attnb, out1);
  k_gemm<1><<<dim3(6, 256), 256, 0, stream>>>(out1, WpT, nullptr, nullptr, nullptr, outF, b_proj);
}

// Round 2
// 318.724 us; speedup vs baseline: 1.1127x; 1.1127x over previous
//
#include <hip/hip_runtime.h>
#include <stdint.h>

typedef __attribute__((ext_vector_type(4))) float          f32x4;
typedef __attribute__((ext_vector_type(8))) short          bf16x8;
typedef __attribute__((ext_vector_type(8))) unsigned short u16x8;
typedef __attribute__((ext_vector_type(4))) unsigned short u16x4;

static __device__ __forceinline__ unsigned short f2bf(float f){
  uint32_t u = __builtin_bit_cast(uint32_t, f);
  u += 0x7FFFu + ((u >> 16) & 1u);          // RNE
  return (unsigned short)(u >> 16);
}
static __device__ __forceinline__ float bf2f(unsigned short h){
  uint32_t u = ((uint32_t)h) << 16;
  return __builtin_bit_cast(float, u);
}

// ---------------- elementwise convert f32 -> bf16 (8/thread) ----------------
__global__ void k_cvt(const float* __restrict__ in, unsigned short* __restrict__ out, long n){
  long i = ((long)blockIdx.x * blockDim.x + threadIdx.x) * 8;
  if (i >= n) return;
  const f32x4* p = (const f32x4*)(in + i);
  f32x4 a = p[0], b = p[1];
  u16x8 o;
  #pragma unroll
  for (int j = 0; j < 4; j++){ o[j] = f2bf(a[j]); o[4+j] = f2bf(b[j]); }
  *(u16x8*)(out + i) = o;
}

// ---------------- tiled transpose+convert: in[R][C] f32 -> out[C][R] bf16 ----
__global__ void k_tconv(const float* __restrict__ in, unsigned short* __restrict__ out, int R, int C){
  __shared__ float tl[64][65];
  const int c0 = blockIdx.x * 64, r0 = blockIdx.y * 64;
  const int t = threadIdx.x;
  {
    const int lr = t >> 2, lc = (t & 3) * 16;
    const f32x4* s = (const f32x4*)(in + (long)(r0 + lr) * C + c0 + lc);
    #pragma unroll
    for (int q = 0; q < 4; q++){
      f32x4 v = s[q];
      #pragma unroll
      for (int j = 0; j < 4; j++) tl[lr][lc + q*4 + j] = v[j];
    }
  }
  __syncthreads();
  {
    const int oc = t >> 2, orr = (t & 3) * 16;
    u16x8 o0, o1;
    #pragma unroll
    for (int i = 0; i < 8; i++){ o0[i] = f2bf(tl[orr + i][oc]); o1[i] = f2bf(tl[orr + 8 + i][oc]); }
    u16x8* dst = (u16x8*)(out + (long)(c0 + oc) * R + r0 + orr);
    dst[0] = o0; dst[1] = o1;
  }
}

// ================= 256x256 8-phase counted-vmcnt GEMM (T1+T2+T3+T4+T5) =======
// BM=BN=256, BK=64, 512 threads = 8 waves (2M x 4N), per-wave out 128x64.
// LDS: 2 buffers x {A,B} x 2 kk-halves, each slot [256 rows][32 k] bf16 = 16KB.
// Swizzle: physical ko = ko ^ ((row ^ row>>2)&3)  (bits[5:4] XOR, involution).
// Stage = 1 slot = 2 x global_load_lds(16B)/thread, linear LDS dest,
// inverse-swizzled global source. vmcnt(6) at phases 4/8 only (0 on last iter).

static __device__ __forceinline__ void stage2(const unsigned short* __restrict__ G, int row0, int ke,
                                              char* lds_slot, int t){
  #pragma unroll
  for (int l = 0; l < 2; l++){
    const int r  = l*128 + (t >> 2);
    const int ko = (t & 3) ^ ((r ^ (r >> 2)) & 3);
    const char* src = (const char*)(G + (long)(row0 + r) * 768 + ke + ko * 8);
    char* dst = lds_slot + l*8192 + (t & 0x1C0) * 16;          // wave-uniform base
    __builtin_amdgcn_global_load_lds((const __attribute__((address_space(1))) unsigned int*)src,
                                     (__attribute__((address_space(3))) unsigned int*)dst, 16, 0, 0);
  }
}

static __device__ __forceinline__ bf16x8 ldfrag(const char* slot, int row, int ko){
  const int k2 = (ko ^ (row ^ (row >> 2))) & 3;
  return *(const bf16x8*)(slot + row*64 + k2*16);
}

#define PHASE(BUF, KK, MH, STAGE_STMT, WAIT_STMT) do {                         \
    bf16x8 af[4];                                                              \
    if (MH == 0) {                                                             \
      _Pragma("unroll")                                                        \
      for (int ni = 0; ni < 4; ni++)                                           \
        bq[ni] = ldfrag(sB[BUF][KK], wn*64 + ni*16 + arow, ko);                \
    }                                                                          \
    _Pragma("unroll")                                                          \
    for (int mi = 0; mi < 4; mi++)                                             \
      af[mi] = ldfrag(sA[BUF][KK], wm*128 + MH*64 + mi*16 + arow, ko);         \
    __builtin_amdgcn_s_barrier();                                              \
    __builtin_amdgcn_s_setprio(1);                                             \
    _Pragma("unroll")                                                          \
    for (int mi = 0; mi < 4; mi++)                                             \
      _Pragma("unroll")                                                        \
      for (int ni = 0; ni < 4; ni++)                                           \
        acc[MH*4+mi][ni] = __builtin_amdgcn_mfma_f32_16x16x32_bf16(            \
            af[mi], bq[ni], acc[MH*4+mi][ni], 0, 0, 0);                        \
    __builtin_amdgcn_s_setprio(0);                                             \
    STAGE_STMT;                                                                \
    WAIT_STMT;                                                                 \
    __builtin_amdgcn_s_barrier();                                              \
  } while(0)

// MODE 0: A=x_bf[32768][768], BT=WT[2304][768] -> QT/KT (transposed) + V
// MODE 1: A=out1[32768][768], BT=WpT[768][768] -> OUTF fp32 + bias
template<int MODE>
__global__ __launch_bounds__(512, 2)
void k_gemm2(const unsigned short* __restrict__ A, const unsigned short* __restrict__ BT,
             unsigned short* __restrict__ QT, unsigned short* __restrict__ KT,
             unsigned short* __restrict__ V, float* __restrict__ OUTF,
             const float* __restrict__ bias)
{
  __shared__ __attribute__((aligned(16))) char lds[131072];
  constexpr int NT = (MODE == 0) ? 9 : 3;
  constexpr int NWG = NT * 128;
  const int o  = blockIdx.x;
  const int wg = (o & 7) * (NWG >> 3) + (o >> 3);          // bijective XCD swizzle
  const int jt = wg % NT, mt = wg / NT;
  const int m0 = mt * 256, j0 = jt * 256;
  const int t = threadIdx.x, lane = t & 63, w = t >> 6;
  const int wm = w >> 2, wn = w & 3;
  const int arow = lane & 15, ko = lane >> 4;

  char* const sA[2][2] = {{lds,           lds + 16384},
                          {lds + 65536,   lds + 65536 + 16384}};
  char* const sB[2][2] = {{lds + 32768,   lds + 49152},
                          {lds + 65536 + 32768, lds + 65536 + 49152}};

  f32x4 acc[8][4] = {};

  // prologue: tile0 (buf0) fully; tile1 (buf1) all but A1 (staged at iter0-ph1)
  stage2(A,  m0, 0,   sA[0][0], t);
  stage2(A,  m0, 32,  sA[0][1], t);
  stage2(BT, j0, 0,   sB[0][0], t);
  stage2(BT, j0, 32,  sB[0][1], t);
  stage2(BT, j0, 64,  sB[1][0], t);
  stage2(A,  m0, 64,  sA[1][0], t);
  stage2(BT, j0, 96,  sB[1][1], t);
  asm volatile("s_waitcnt vmcnt(6)" ::: "memory");
  __builtin_amdgcn_s_barrier();

  #pragma unroll 1
  for (int it = 0; it < 6; ++it){
    const int t1 = 2*it + 1, t2 = 2*it + 2, t3 = 2*it + 3;
    bf16x8 bq[4];
    // ---- tile t0 = 2*it (buf0) ----
    PHASE(0,0,0, { stage2(A, m0, t1*64+32, sA[1][1], t); }, ;);                  // A1 of t1
    PHASE(0,0,1, { if (t2 < 12) stage2(BT, j0, t2*64,    sB[0][0], t); }, ;);    // B0 of t2
    PHASE(0,1,0, { if (t2 < 12) stage2(A,  m0, t2*64,    sA[0][0], t); }, ;);    // A0 of t2
    PHASE(0,1,1, { if (t2 < 12) stage2(BT, j0, t2*64+32, sB[0][1], t); },
                 { if (it == 5) asm volatile("s_waitcnt vmcnt(0)" ::: "memory");
                   else         asm volatile("s_waitcnt vmcnt(6)" ::: "memory"); });
    // ---- tile t1 (buf1) ----
    PHASE(1,0,0, { if (t2 < 12) stage2(A,  m0, t2*64+32, sA[0][1], t); }, ;);    // A1 of t2
    PHASE(1,0,1, { if (t3 < 12) stage2(BT, j0, t3*64,    sB[1][0], t); }, ;);    // B0 of t3
    PHASE(1,1,0, { if (t3 < 12) stage2(A,  m0, t3*64,    sA[1][0], t); }, ;);    // A0 of t3
    PHASE(1,1,1, { if (t3 < 12) stage2(BT, j0, t3*64+32, sB[1][1], t); },
                 { if (it == 5) asm volatile("s_waitcnt vmcnt(0)" ::: "memory");
                   else         asm volatile("s_waitcnt vmcnt(6)" ::: "memory"); });
  }

  if (MODE == 0){
    const int b = m0 >> 12;
    if (j0 < 1536){
      const int nb = (m0 & 4095) + wm*128 + (lane >> 4)*4;
      #pragma unroll
      for (int mi = 0; mi < 8; mi++){
        #pragma unroll
        for (int ni = 0; ni < 4; ni++){
          const int jc = j0 + wn*64 + ni*16 + (lane & 15);
          const int s  = (jc >= 768);
          const int jl = jc - s * 768;
          const int h  = jl / 48;
          const int c  = jl - h * 48;
          unsigned short* dst = (s ? KT : QT) + (((long)(b*16 + h) * 48 + c) << 12) + nb + mi*16;
          u16x4 pk;
          #pragma unroll
          for (int r = 0; r < 4; r++) pk[r] = f2bf(acc[mi][ni][r]);
          *(u16x4*)dst = pk;
        }
      }
    } else {
      #pragma unroll
      for (int mi = 0; mi < 8; mi++){
        #pragma unroll
        for (int ni = 0; ni < 4; ni++){
          const int jv = (j0 - 1536) + wn*64 + ni*16 + (lane & 15);
          const long mr = (long)m0 + wm*128 + mi*16 + (lane >> 4)*4;
          #pragma unroll
          for (int r = 0; r < 4; r++) V[(mr + r) * 768 + jv] = f2bf(acc[mi][ni][r]);
        }
      }
    }
  } else {
    #pragma unroll
    for (int mi = 0; mi < 8; mi++){
      #pragma unroll
      for (int ni = 0; ni < 4; ni++){
        const int jc = j0 + wn*64 + ni*16 + (lane & 15);
        const float bv = bias[jc];
        const long mr = (long)m0 + wm*128 + mi*16 + (lane >> 4)*4;
        #pragma unroll
        for (int r = 0; r < 4; r++) OUTF[(mr + r) * 768 + jc] = acc[mi][ni][r] + bv;
      }
    }
  }
}

// ---------------- per-row inverse L2 norm over QT||KT rows (4096 each) ------
__global__ void k_norm(const unsigned short* __restrict__ QTKT, float* __restrict__ invn){
  const long row = blockIdx.x;
  const unsigned short* p = QTKT + (row << 12);
  const int l = threadIdx.x;   // 64 threads = 1 wave
  float ss = 0.f;
  #pragma unroll
  for (int i = 0; i < 8; i++){
    u16x8 v = *(const u16x8*)(p + (i*64 + l) * 8);
    #pragma unroll
    for (int j = 0; j < 8; j++){ float f = bf2f(v[j]); ss += f * f; }
  }
  #pragma unroll
  for (int off = 32; off > 0; off >>= 1) ss += __shfl_down(ss, off);
  if (l == 0) invn[row] = 1.0f / fmaxf(sqrtf(ss), 1e-12f);
}

// ---------------- S partials: per (bh, ksp) 48x48 over 1024 n ---------------
__global__ __launch_bounds__(256)
void k_attn_part(const unsigned short* __restrict__ QT, const unsigned short* __restrict__ KT,
                 float* __restrict__ Spart)
{
  __shared__ float Sl[4][2304];
  const int bh = blockIdx.x, ksp = blockIdx.y;
  const int t = threadIdx.x, lane = t & 63, w = t >> 6;
  const unsigned short* qb = QT + ((long)bh * 48 << 12);
  const unsigned short* kb = KT + ((long)bh * 48 << 12);
  const int n00 = ksp * 1024 + w * 256;
  f32x4 acc[3][3] = {};
  for (int kt = 0; kt < 256; kt += 32){
    bf16x8 af[3], bfr[3];
    #pragma unroll
    for (int ci = 0; ci < 3; ci++)
      af[ci]  = *(const bf16x8*)(qb + ((long)(ci*16 + (lane & 15)) << 12) + n00 + kt + (lane >> 4) * 8);
    #pragma unroll
    for (int di = 0; di < 3; di++)
      bfr[di] = *(const bf16x8*)(kb + ((long)(di*16 + (lane & 15)) << 12) + n00 + kt + (lane >> 4) * 8);
    #pragma unroll
    for (int ci = 0; ci < 3; ci++)
      #pragma unroll
      for (int di = 0; di < 3; di++)
        acc[ci][di] = __builtin_amdgcn_mfma_f32_16x16x32_bf16(af[ci], bfr[di], acc[ci][di], 0, 0, 0);
  }
  #pragma unroll
  for (int ci = 0; ci < 3; ci++)
    #pragma unroll
    for (int di = 0; di < 3; di++)
      #pragma unroll
      for (int r = 0; r < 4; r++)
        Sl[w][(ci*16 + (lane >> 4)*4 + r) * 48 + di*16 + (lane & 15)] = acc[ci][di][r];
  __syncthreads();
  float* outp = Spart + ((long)ksp * 128 + bh) * 2304;
  for (int idx = t; idx < 2304; idx += 256)
    outp[idx] = Sl[0][idx] + Sl[1][idx] + Sl[2][idx] + Sl[3][idx];
}

// ---------------- reduce partials, scale by invnorms*temp, softmax ----------
__global__ void k_softmax(const float* __restrict__ Spart, const float* __restrict__ invn,
                          const float* __restrict__ temp, unsigned short* __restrict__ attn)
{
  const int bh = blockIdx.x, h = bh & 15;
  const int c = threadIdx.x;   // 64 threads, 48 active
  if (c < 48){
    const float invq = invn[bh*48 + c];
    const float tq = temp[h];
    float row[48];
    #pragma unroll
    for (int d = 0; d < 48; d++){
      long base = ((long)bh * 48 + c) * 48 + d;
      float v = Spart[base] + Spart[base + 128L*2304] + Spart[base + 256L*2304] + Spart[base + 384L*2304];
      row[d] = v * invq * invn[6144 + bh*48 + d] * tq;
    }
    float mx = -1e30f;
    #pragma unroll
    for (int d = 0; d < 48; d++) mx = fmaxf(mx, row[d]);
    float s = 0.f;
    #pragma unroll
    for (int d = 0; d < 48; d++){ row[d] = expf(row[d] - mx); s += row[d]; }
    const float inv = 1.0f / s;
    unsigned short* o = attn + ((long)bh * 48 + c) * 64;
    #pragma unroll
    for (int d = 0; d < 48; d++) o[d] = f2bf(row[d] * inv);
    #pragma unroll
    for (int d = 48; d < 64; d++) o[d] = 0;
  }
}

// ---------------- AV: out1[m][h*48+c] = sum_d v[m][d]*attn[c][d] ------------
__global__ __launch_bounds__(256)
void k_av(const unsigned short* __restrict__ V, const unsigned short* __restrict__ attn,
          unsigned short* __restrict__ out1)
{
  const int gid = blockIdx.x;
  const int nt = gid & 15, bh = gid >> 4, b = bh >> 4, h = bh & 15;
  const int t = threadIdx.x, lane = t & 63, w = t >> 6;
  const int n0 = nt * 256 + w * 64;
  const unsigned short* vb = V + (long)b * 4096 * 768 + h * 48;
  const unsigned short* ab = attn + (long)bh * 48 * 64;
  f32x4 acc[4][3] = {};
  #pragma unroll
  for (int kt = 0; kt < 64; kt += 32){
    bf16x8 bfr[3];
    #pragma unroll
    for (int ci = 0; ci < 3; ci++)
      bfr[ci] = *(const bf16x8*)(ab + (ci*16 + (lane & 15)) * 64 + kt + (lane >> 4) * 8);
    #pragma unroll
    for (int nf = 0; nf < 4; nf++){
      bf16x8 a = *(const bf16x8*)(vb + (long)(n0 + nf*16 + (lane & 15)) * 768 + kt + (lane >> 4) * 8);
      #pragma unroll
      for (int ci = 0; ci < 3; ci++)
        acc[nf][ci] = __builtin_amdgcn_mfma_f32_16x16x32_bf16(a, bfr[ci], acc[nf][ci], 0, 0, 0);
    }
  }
  #pragma unroll
  for (int nf = 0; nf < 4; nf++)
    #pragma unroll
    for (int ci = 0; ci < 3; ci++)
      #pragma unroll
      for (int r = 0; r < 4; r++){
        long m = (long)b * 4096 + n0 + nf*16 + (lane >> 4)*4 + r;
        out1[m * 768 + h*48 + ci*16 + (lane & 15)] = f2bf(acc[nf][ci][r]);
      }
}

extern "C" void kernel_launch(void* const* d_in, const int* in_sizes, int n_in,
                              void* d_out, int out_size, void* d_ws, size_t ws_size,
                              hipStream_t stream)
{
  (void)in_sizes; (void)n_in; (void)out_size; (void)ws_size;
  const float* x      = (const float*)d_in[0];
  const float* w_qkv  = (const float*)d_in[1];
  const float* temp   = (const float*)d_in[2];
  const float* w_proj = (const float*)d_in[3];
  const float* b_proj = (const float*)d_in[4];
  float* outF = (float*)d_out;

  char* ws = (char*)d_ws;
  size_t off = 0;
  auto alloc = [&](size_t bytes)->char*{ char* p = ws + off; off += (bytes + 255) & ~(size_t)255; return p; };

  unsigned short* x_bf = (unsigned short*)alloc(50331648);            // [32768][768] bf16
  unsigned short* WT   = (unsigned short*)alloc(3538944);             // [2304][768] bf16
  unsigned short* WpT  = (unsigned short*)alloc(1179648);             // [768][768] bf16
  unsigned short* QT   = (unsigned short*)alloc(100663296);           // QT||KT [6144][4096] bf16 each
  unsigned short* KT   = QT + (long)6144 * 4096;
  unsigned short* V    = (unsigned short*)alloc(50331648 + 2048);     // [32768][768] bf16 + slack row
  float* invn          = (float*)alloc(12288 * 4);                    // [2][8][16][48]
  float* Spart         = (float*)alloc(4L * 128 * 2304 * 4);          // [4][128][48][48] f32
  unsigned short* attnb= (unsigned short*)alloc(128L * 48 * 64 * 2);  // [128][48][64] bf16, zero-padded
  unsigned short* out1 = QT;   // alias: QT fully consumed before AV writes

  hipMemsetAsync(V + 25165824, 0, 2048, stream);

  k_cvt<<<12288, 256, 0, stream>>>(x, x_bf, 25165824L);
  k_tconv<<<dim3(36, 12), 256, 0, stream>>>(w_qkv, WT, 768, 2304);
  k_tconv<<<dim3(12, 12), 256, 0, stream>>>(w_proj, WpT, 768, 768);
  k_gemm2<0><<<1152, 512, 0, stream>>>(x_bf, WT, QT, KT, V, nullptr, nullptr);
  k_norm<<<12288, 64, 0, stream>>>(QT, invn);
  k_attn_part<<<dim3(128, 4), 256, 0, stream>>>(QT, KT, Spart);
  k_softmax<<<128, 64, 0, stream>>>(Spart, invn, temp, attnb);
  k_av<<<2048, 256, 0, stream>>>(V, attnb, out1);
  k_gemm2<1><<<384, 512, 0, stream>>>(out1, WpT, nullptr, nullptr, nullptr, outF, b_proj);
}